// Round 13
// baseline (258.103 us; speedup 1.0000x reference)
//
#include <hip/hip_runtime.h>
#include <hip/hip_bf16.h>

#define N_NODES 50000
#define N_EDGES 800000
#define D_IN    512
#define D_OUT   256
#define NBLK_SCAN ((N_NODES + 1023) / 1024)   // 49
#define GEMM_NWG (((N_NODES + 127) / 128) * 2)  // 782
#define GEMM_Q   (GEMM_NWG / 8)                  // 97
#define GEMM_R   (GEMM_NWG % 8)                  // 6

typedef short s8v   __attribute__((ext_vector_type(8)));
typedef float f32x4 __attribute__((ext_vector_type(4)));

__device__ __forceinline__ unsigned short bf16b(float f) {
    __hip_bfloat16 h = __float2bfloat16(f);
    return *reinterpret_cast<unsigned short*>(&h);
}
__device__ __forceinline__ float bflo(unsigned u) { return __uint_as_float(u << 16); }
__device__ __forceinline__ float bfhi(unsigned u) { return __uint_as_float(u & 0xffff0000u); }

__device__ __forceinline__ int wave_incl_scan(int v, int lane) {
    #pragma unroll
    for (int d = 1; d < 64; d <<= 1) {
        int u = __shfl_up(v, d, 64);
        if (lane >= d) v += u;
    }
    return v;
}

// ============ W transpose + bf16 convert; also zeroes cnt (saves a memset) ====
__global__ void k_wt(const float* __restrict__ W, unsigned short* __restrict__ Wt,
                     int* __restrict__ cnt) {
    int k = blockIdx.x;      // 512
    int n = threadIdx.x;     // 256
    Wt[(size_t)n * D_IN + k] = bf16b(W[(size_t)k * D_OUT + n]);
    int t = blockIdx.x * 256 + threadIdx.x;
    if (t < N_NODES) cnt[t] = 0;
}

// ============ CSR build ============

__global__ void k_count(const int* __restrict__ col, int* __restrict__ cnt) {
    int i = (blockIdx.x * 256 + threadIdx.x) * 2;
    if (i < N_EDGES) {                            // N_EDGES even
        int2 c = *(const int2*)&col[i];
        atomicAdd(&cnt[c.x], 1);
        atomicAdd(&cnt[c.y], 1);
    }
}

__launch_bounds__(256)
__global__ void k_scan1(const int* __restrict__ cnt, int* __restrict__ bsum) {
    const int t = threadIdx.x, b = blockIdx.x;
    const int idx = b * 1024 + t * 4;
    int4 v = make_int4(0, 0, 0, 0);
    if (idx < N_NODES) v = *(const int4*)&cnt[idx];
    int s = v.x + v.y + v.z + v.w;
    #pragma unroll
    for (int d = 1; d < 64; d <<= 1) s += __shfl_xor(s, d, 64);
    __shared__ int ws[4];
    if ((t & 63) == 0) ws[t >> 6] = s;
    __syncthreads();
    if (t == 0) bsum[b] = ws[0] + ws[1] + ws[2] + ws[3];
}

// in-block exclusive scan + self-computed block offset
__launch_bounds__(256)
__global__ void k_scan3(const int* __restrict__ cnt, const int* __restrict__ bsum,
                        int* __restrict__ row_ptr, float* __restrict__ dinv,
                        int* __restrict__ cursor) {
    const int t = threadIdx.x, b = blockIdx.x;
    const int lane = t & 63, wv = t >> 6;
    const int idx = b * 1024 + t * 4;
    int4 v = make_int4(0, 0, 0, 0);
    if (idx < N_NODES) v = *(const int4*)&cnt[idx];
    int s = v.x + v.y + v.z + v.w;
    int isc = wave_incl_scan(s, lane);
    __shared__ int wsum[4];
    __shared__ int s_boff;
    if (lane == 63) wsum[wv] = isc;
    if (t < 64) {                                  // wave 0: sum of bsum[0..b)
        int u = (t < b) ? bsum[t] : 0;             // b <= 48 < 64
        #pragma unroll
        for (int d = 1; d < 64; d <<= 1) u += __shfl_xor(u, d, 64);
        if (t == 0) s_boff = u;
    }
    __syncthreads();
    int off = s_boff;
    #pragma unroll
    for (int i = 0; i < 4; ++i)
        if (i < wv) off += wsum[i];
    int p0 = off + isc - s;
    int p1 = p0 + v.x;
    int p2 = p1 + v.y;
    int p3 = p2 + v.z;
    if (idx < N_NODES) {
        row_ptr[idx + 0] = p0; cursor[idx + 0] = p0; dinv[idx + 0] = rsqrtf(1.f + (float)v.x);
        row_ptr[idx + 1] = p1; cursor[idx + 1] = p1; dinv[idx + 1] = rsqrtf(1.f + (float)v.y);
        row_ptr[idx + 2] = p2; cursor[idx + 2] = p2; dinv[idx + 2] = rsqrtf(1.f + (float)v.z);
        row_ptr[idx + 3] = p3; cursor[idx + 3] = p3; dinv[idx + 3] = rsqrtf(1.f + (float)v.w);
    }
    if (b == 0 && t == 0) row_ptr[N_NODES] = N_EDGES;
}

__global__ void k_fill(const int* __restrict__ row, const int* __restrict__ col,
                       int* __restrict__ cursor, int* __restrict__ csr_src) {
    int i = (blockIdx.x * 256 + threadIdx.x) * 2;
    if (i < N_EDGES) {
        int2 c = *(const int2*)&col[i];
        int2 r = *(const int2*)&row[i];
        int p0 = atomicAdd(&cursor[c.x], 1);
        csr_src[p0] = r.x;
        int p1 = atomicAdd(&cursor[c.y], 1);
        csr_src[p1] = r.y;
    }
}

// ============ MFMA GEMM: yb = bf16(dinv[r] * (x @ W)) ============
// Rounds 10-12 lesson: every LDS-staged variant drains vmcnt(0) at a barrier
// each K-step -> outstanding loads collapse -> ~1.2 TB/s effective fetch ->
// 52-102MB takes 45-85us. THIS version has NO LDS and NO BARRIERS: each lane
// loads its MFMA fragments DIRECTLY from global. The 16x16x32 A-frag pattern
// (lane l: row l&15, k-chunk (l>>4)*8) is natively coalesced: one wave-instr
// = 16 rows x one 128B line each (kk*4 is 128-aligned). Waves run as fully
// independent deep-MLP streams; the compiler pipelines loads across unrolled
// k-steps since nothing blocks it. A read 2x (n-split) but x (102MB) is
// L3-resident; Wt (256KB) is L2-resident.
__launch_bounds__(256)
__global__ void k_gemm(const float* __restrict__ A,            // [N_NODES,512] fp32
                       const unsigned short* __restrict__ Wt,  // [256,512] bf16
                       const float* __restrict__ dinv,
                       unsigned short* __restrict__ yb)        // [N_NODES,256] bf16
{
    // bijective XCD swizzle (m204)
    int orig = blockIdx.x;
    int xcd = orig % 8, pos = orig / 8;
    int wg = (xcd < GEMM_R) ? xcd * (GEMM_Q + 1) + pos
                            : GEMM_R * (GEMM_Q + 1) + (xcd - GEMM_R) * GEMM_Q + pos;
    const int nt = wg & 1;
    const int mt = wg >> 1;
    const int m0 = mt * 128;
    const int n0 = nt * 128;

    const int t  = threadIdx.x;
    const int w  = t >> 6;
    const int l  = t & 63;
    const int wm = (w >> 1) * 64;
    const int wn = (w & 1) * 64;
    const int lr = l & 15;
    const int lk = l >> 4;

    // per-lane fragment base pointers (k-chunk (l>>4)*8 baked in)
    const float* arow[4];
    const unsigned short* brow[4];
    #pragma unroll
    for (int f = 0; f < 4; ++f) {
        int r = m0 + wm + f * 16 + lr;
        if (r >= N_NODES) r = 0;                 // tail clamp; outputs guarded
        arow[f] = A  + (size_t)r * D_IN + lk * 8;
        int c = n0 + wn + f * 16 + lr;
        brow[f] = Wt + (size_t)c * D_IN + lk * 8;
    }

    f32x4 acc[4][4] = {};

    #pragma unroll 4
    for (int kk = 0; kk < D_IN; kk += 32) {
        // issue all 12 loads for this k-step back-to-back
        float4 a0[4], a1[4];
        uint4  bq[4];
        #pragma unroll
        for (int f = 0; f < 4; ++f) {
            a0[f] = *(const float4*)(arow[f] + kk);
            a1[f] = *(const float4*)(arow[f] + kk + 4);
        }
        #pragma unroll
        for (int f = 0; f < 4; ++f)
            bq[f] = *(const uint4*)(brow[f] + kk);

        s8v af[4], bf[4];
        #pragma unroll
        for (int f = 0; f < 4; ++f) {
            union { s8v v; unsigned short h[8]; } u;
            u.h[0] = bf16b(a0[f].x); u.h[1] = bf16b(a0[f].y);
            u.h[2] = bf16b(a0[f].z); u.h[3] = bf16b(a0[f].w);
            u.h[4] = bf16b(a1[f].x); u.h[5] = bf16b(a1[f].y);
            u.h[6] = bf16b(a1[f].z); u.h[7] = bf16b(a1[f].w);
            af[f] = u.v;
            bf[f] = *(const s8v*)&bq[f];
        }
        #pragma unroll
        for (int fm = 0; fm < 4; ++fm)
            #pragma unroll
            for (int fn = 0; fn < 4; ++fn)
                acc[fm][fn] = __builtin_amdgcn_mfma_f32_16x16x32_bf16(
                    af[fm], bf[fn], acc[fm][fn], 0, 0, 0);
    }

    // C/D layout: col = lane&15, row = (lane>>4)*4 + j
    #pragma unroll
    for (int fm = 0; fm < 4; ++fm) {
        #pragma unroll
        for (int j = 0; j < 4; ++j) {
            int row = m0 + wm + fm * 16 + lk * 4 + j;
            if (row < N_NODES) {
                float s = dinv[row];
                #pragma unroll
                for (int fn = 0; fn < 4; ++fn) {
                    int col = n0 + wn + fn * 16 + lr;
                    yb[(size_t)row * D_OUT + col] = bf16b(acc[fm][fn][j] * s);
                }
            }
        }
    }
}

// ============ gather: out[c] = relu(dinv[c]*(yb[c] + sum yb[src]) + b) ============
// eg-split layout: wave = 2 edge-groups x 32 col-slots of 16B -> each load
// instruction moves 1KB covering TWO edges. Full rounds of 8 edges/half
// unmasked; tail = masked rounds of 4/half (clamped loads are L1-cheap).
__device__ __forceinline__ void add8(float* acc, uint4 q) {
    unsigned x;
    x = q.x; acc[0] += bflo(x); acc[1] += bfhi(x);
    x = q.y; acc[2] += bflo(x); acc[3] += bfhi(x);
    x = q.z; acc[4] += bflo(x); acc[5] += bfhi(x);
    x = q.w; acc[6] += bflo(x); acc[7] += bfhi(x);
}

__launch_bounds__(256)
__global__ void k_gather(const int* __restrict__ row_ptr, const int* __restrict__ csr_src,
                         const unsigned short* __restrict__ yb, const float* __restrict__ dinv,
                         const float* __restrict__ bias, float* __restrict__ out)
{
    const int c  = blockIdx.x * 4 + (threadIdx.x >> 6);
    const int l  = threadIdx.x & 63;
    const int eg = l >> 5;              // edge-group 0/1
    const int cs = l & 31;              // col-slot: cols cs*8 .. cs*8+7
    const size_t colb = (size_t)cs * 8;

    float acc[8] = {0.f,0.f,0.f,0.f,0.f,0.f,0.f,0.f};

    const int s = row_ptr[c];
    const int e = row_ptr[c + 1];

    int i = s + eg;
    while (i + 14 < e) {                // 8 edges per half, unmasked
        int r[8];
        #pragma unroll
        for (int u = 0; u < 8; ++u) r[u] = csr_src[i + 2 * u];
        uint4 v[8];
        #pragma unroll
        for (int u = 0; u < 8; ++u) v[u] = *(const uint4*)&yb[(size_t)r[u] * D_OUT + colb];
        #pragma unroll
        for (int u = 0; u < 8; ++u) add8(acc, v[u]);
        i += 16;
    }
    while (i < e) {                     // masked rounds of 4 per half
        int r[4];
        #pragma unroll
        for (int u = 0; u < 4; ++u) {
            int p = i + 2 * u;
            r[u] = csr_src[p < e ? p : e - 1];
        }
        uint4 v[4];
        #pragma unroll
        for (int u = 0; u < 4; ++u) v[u] = *(const uint4*)&yb[(size_t)r[u] * D_OUT + colb];
        #pragma unroll
        for (int u = 0; u < 4; ++u)
            if (i + 2 * u < e) add8(acc, v[u]);
        i += 8;
    }

    // combine the two edge-group halves
    #pragma unroll
    for (int u = 0; u < 8; ++u) acc[u] += __shfl_xor(acc[u], 32, 64);

    // self-loop term
    uint4 sv = *(const uint4*)&yb[(size_t)c * D_OUT + colb];
    add8(acc, sv);

    if (eg == 0) {
        const float sc = dinv[c];
        float4 b0 = *(const float4*)&bias[colb];
        float4 b1 = *(const float4*)&bias[colb + 4];
        float4 o0, o1;
        o0.x = fmaxf(fmaf(acc[0], sc, b0.x), 0.f);
        o0.y = fmaxf(fmaf(acc[1], sc, b0.y), 0.f);
        o0.z = fmaxf(fmaf(acc[2], sc, b0.z), 0.f);
        o0.w = fmaxf(fmaf(acc[3], sc, b0.w), 0.f);
        o1.x = fmaxf(fmaf(acc[4], sc, b1.x), 0.f);
        o1.y = fmaxf(fmaf(acc[5], sc, b1.y), 0.f);
        o1.z = fmaxf(fmaf(acc[6], sc, b1.z), 0.f);
        o1.w = fmaxf(fmaf(acc[7], sc, b1.w), 0.f);
        float* dst = &out[(size_t)c * D_OUT + colb];
        *(float4*)dst       = o0;
        *(float4*)(dst + 4) = o1;
    }
}

extern "C" void kernel_launch(void* const* d_in, const int* in_sizes, int n_in,
                              void* d_out, int out_size, void* d_ws, size_t ws_size,
                              hipStream_t stream) {
    const float* x   = (const float*)d_in[0];
    const int*   ei  = (const int*)d_in[1];
    const float* W   = (const float*)d_in[2];
    const float* b   = (const float*)d_in[3];
    float*       out = (float*)d_out;

    const int* row = ei;
    const int* col = ei + N_EDGES;

    char* p = (char*)d_ws;
    unsigned short* yb = (unsigned short*)p;  p += (size_t)N_NODES * D_OUT * 2;   // 25.6 MB
    unsigned short* Wt = (unsigned short*)p;  p += (size_t)D_OUT * D_IN * 2;      // 256 KB
    int*   csr_src = (int*)p;                 p += (size_t)N_EDGES * 4;           // 3.2 MB
    int*   cnt     = (int*)p;                 p += (size_t)N_NODES * 4;
    int*   row_ptr = (int*)p;                 p += (size_t)(N_NODES + 4) * 4;
    int*   cursor  = (int*)p;                 p += (size_t)N_NODES * 4;
    float* dinv    = (float*)p;               p += (size_t)N_NODES * 4;
    int*   bsum    = (int*)p;                 p += (size_t)NBLK_SCAN * 4;

    k_wt   <<<D_IN, D_OUT, 0, stream>>>(W, Wt, cnt);   // also zeroes cnt
    k_count<<<(N_EDGES / 2 + 255) / 256, 256, 0, stream>>>(col, cnt);
    k_scan1<<<NBLK_SCAN, 256, 0, stream>>>(cnt, bsum);
    k_scan3<<<NBLK_SCAN, 256, 0, stream>>>(cnt, bsum, row_ptr, dinv, cursor);
    k_fill <<<(N_EDGES / 2 + 255) / 256, 256, 0, stream>>>(row, col, cursor, csr_src);

    k_gemm<<<GEMM_NWG, 256, 0, stream>>>(x, Wt, dinv, yb);

    k_gather<<<N_NODES / 4, 256, 0, stream>>>(row_ptr, csr_src, yb, dinv, b, out);
}